// Round 1
// 32.267 us; speedup vs baseline: 1.0231x; 1.0231x over previous
//
#include <hip/hip_runtime.h>

#define BDIM 512
#define NLEN 9000
#define NV4  2250        // NLEN / 4 (exact)
#define KMAX 5           // ceil(NV4 / BDIM)
#define NWAVE (BDIM / 64)

__global__ __launch_bounds__(BDIM, 8) void PeakbasedDetector_43542378447356_kernel(
    const float* __restrict__ sig,
    const float* __restrict__ times,
    float* __restrict__ out)
{
    // Boundary values only: chunk i stores x at bnd[2+2i], w at bnd[3+2i].
    // bnd[1] and bnd[2+2*NV4] are +INF sentinels so the detect loop is branch-free:
    //   L(chunk i) = bnd[1+2i]  (w of chunk i-1; +INF kills peak at element 0)
    //   R(chunk i) = bnd[4+2i]  (x of chunk i+1; +INF kills peak at element N-1)
    __shared__ float bnd[2 * NV4 + 4];                 // 18.0 KB
    __shared__ float red_mn[NWAVE], red_mx[NWAVE];
    __shared__ int   red_c[NWAVE], red_fi[NWAVE], red_li[NWAVE];

    const int row  = blockIdx.x;
    const int tid  = threadIdx.x;
    const int lane = tid & 63;
    const int wid  = tid >> 6;
    const float* srow = sig + (size_t)row * NLEN;

    if (tid == 0) {
        bnd[1]            = 3.402823466e+38f;          // left sentinel
        bnd[2 + 2 * NV4]  = 3.402823466e+38f;          // right sentinel
    }

    // ---- 1. single coalesced read: float4 slices -> registers; track min/max;
    //         stash chunk-boundary pair (x,w) to LDS with one ds_write_b64
    float4 v[KMAX];
    float mn =  3.402823466e+38f;
    float mx = -3.402823466e+38f;
    #pragma unroll
    for (int k = 0; k < KMAX; ++k) {
        int i4 = tid + k * BDIM;
        if (i4 < NV4) {
            v[k] = ((const float4*)srow)[i4];
            *(float2*)&bnd[2 + 2 * i4] = make_float2(v[k].x, v[k].w);
            // linear chains -> v_min3/v_max3 fusion
            mn = fminf(fminf(fminf(fminf(mn, v[k].x), v[k].y), v[k].z), v[k].w);
            mx = fmaxf(fmaxf(fmaxf(fmaxf(mx, v[k].x), v[k].y), v[k].z), v[k].w);
        }
    }

    // ---- 2. block min/max reduction (wave shfl, then LDS across 8 waves)
    #pragma unroll
    for (int off = 32; off > 0; off >>= 1) {
        mn = fminf(mn, __shfl_down(mn, off, 64));
        mx = fmaxf(mx, __shfl_down(mx, off, 64));
    }
    if (lane == 0) { red_mn[wid] = mn; red_mx[wid] = mx; }
    __syncthreads();               // also publishes bnd (incl. sentinels)
    mn = red_mn[0]; mx = red_mx[0];
    #pragma unroll
    for (int w = 1; w < NWAVE; ++w) {
        mn = fminf(mn, red_mn[w]);
        mx = fmaxf(mx, red_mx[w]);
    }
    // norm >= 0.3  <=>  sig >= mn + 0.3*d  (division by d>0 is monotone;
    // ulp-boundary ties shift count by ±1 -> ~0.05 ms, well inside threshold)
    const float thr = mn + 0.3f * ((mx - mn) + 1e-8f);

    // ---- 3. peak detection straight from registers.
    //         a>=b && a>=thr  <=>  a >= fmax(b, thr): one cmp fewer per element.
    int cnt = 0, mini = NLEN, maxi = -1;
    #pragma unroll
    for (int k = 0; k < KMAX; ++k) {
        int i4 = tid + k * BDIM;
        if (i4 < NV4) {
            const float a = v[k].x, b = v[k].y, c = v[k].z, e = v[k].w;
            const float L = bnd[1 + 2 * i4];           // ds_read2-mergeable pair
            const float R = bnd[4 + 2 * i4];
            const int base = i4 * 4;
            const bool pa = (a > L) & (a >= fmaxf(b, thr));
            const bool pb = (b > a) & (b >= fmaxf(c, thr));
            const bool pc = (c > b) & (c >= fmaxf(e, thr));
            const bool pe = (e > c) & (e >= fmaxf(R, thr));
            cnt += pa + pb + pc + pe;
            // ascending scan order: overwrite == running max; min-select for first
            mini = pa ? min(mini, base    ) : mini;
            mini = pb ? min(mini, base + 1) : mini;
            mini = pc ? min(mini, base + 2) : mini;
            mini = pe ? min(mini, base + 3) : mini;
            maxi = pa ? base     : maxi;
            maxi = pb ? base + 1 : maxi;
            maxi = pc ? base + 2 : maxi;
            maxi = pe ? base + 3 : maxi;
        }
    }

    // ---- 4. block reduce {count, first idx, last idx}
    #pragma unroll
    for (int off = 32; off > 0; off >>= 1) {
        cnt  += __shfl_down(cnt, off, 64);
        mini  = min(mini, __shfl_down(mini, off, 64));
        maxi  = max(maxi, __shfl_down(maxi, off, 64));
    }
    if (lane == 0) { red_c[wid] = cnt; red_fi[wid] = mini; red_li[wid] = maxi; }
    __syncthreads();

    // ---- 5. epilogue: 2 timestamp reads, final formula
    if (tid == 0) {
        int c = 0, fi = NLEN, li = -1;
        #pragma unroll
        for (int w = 0; w < NWAVE; ++w) {
            c += red_c[w];
            fi = min(fi, red_fi[w]);
            li = max(li, red_li[w]);
        }
        float r = 0.0f;
        if (c >= 2) {
            const float* trow = times + (size_t)row * NLEN;
            float tf = trow[fi] * 1000.0f;
            float tl = trow[li] * 1000.0f;
            r = (tl - tf) / (float)(c - 1);
        }
        out[row] = r;
    }
}

extern "C" void kernel_launch(void* const* d_in, const int* in_sizes, int n_in,
                              void* d_out, int out_size, void* d_ws, size_t ws_size,
                              hipStream_t stream) {
    const float* sig   = (const float*)d_in[0];
    const float* times = (const float*)d_in[1];
    float* out = (float*)d_out;
    const int B = out_size;   // 4096 rows
    PeakbasedDetector_43542378447356_kernel<<<B, BDIM, 0, stream>>>(sig, times, out);
}